// Round 1
// baseline (29749.261 us; speedup 1.0000x reference)
//
#include <hip/hip_runtime.h>
#include <hip/hip_bf16.h>
#include <math.h>

// Problem dims
#define T_N   4096
#define IN_N  1024
#define H_N   2048
#define OUT_N 1024

// Recurrence decomposition: KD blocks per direction, each owns RPB rows of Wh.
#define KD  64
#define RPB 32         // H_N / KD
#define RTHREADS 512   // 8 waves

// Workspace byte offsets
#define XW_F_OFF 0ull
#define XW_B_OFF 33554432ull     // 32 MB
#define HF_OFF   67108864ull
#define HB_OFF   100663296ull
#define DF_OFF   134217728ull
#define DB_OFF   134250496ull
// total ~134.3 MB

__global__ __launch_bounds__(256) void init_flags_kernel(unsigned* __restrict__ df,
                                                         unsigned* __restrict__ db) {
  int i = blockIdx.x * blockDim.x + threadIdx.x;
  if (i <= T_N) { df[i] = 0u; db[i] = 0u; }
}

// ---------------------------------------------------------------------------
// Tiled fp32 NT GEMM: C[m][n] = sum_k A[m][k]*B[n][k] + bias[n]
// 64x64 tile, BK=16, 256 threads, 4x4 per thread.
// ---------------------------------------------------------------------------
__global__ __launch_bounds__(256) void gemm_xw_kernel(
    const float* __restrict__ x,
    const float* __restrict__ Wxf, const float* __restrict__ bhf,
    const float* __restrict__ Wxb, const float* __restrict__ bhb,
    float* __restrict__ xwf, float* __restrict__ xwb)
{
  const int dir = blockIdx.z;
  const float* __restrict__ B    = dir ? Wxb : Wxf;
  const float* __restrict__ bias = dir ? bhb : bhf;
  float* __restrict__ C          = dir ? xwb : xwf;
  const int bm0 = blockIdx.y * 64;   // T dim
  const int bn0 = blockIdx.x * 64;   // H dim

  __shared__ float As[16][65];
  __shared__ float Bs[16][65];
  const int tid  = threadIdx.x;
  const int ty   = tid >> 4, tx = tid & 15;
  const int lrow = tid >> 2, lkq = (tid & 3) << 2;
  float acc[4][4] = {};

  for (int k0 = 0; k0 < IN_N; k0 += 16) {
    float4 a4 = *(const float4*)(x + (size_t)(bm0 + lrow) * IN_N + k0 + lkq);
    float4 b4 = *(const float4*)(B + (size_t)(bn0 + lrow) * IN_N + k0 + lkq);
    As[lkq + 0][lrow] = a4.x; As[lkq + 1][lrow] = a4.y;
    As[lkq + 2][lrow] = a4.z; As[lkq + 3][lrow] = a4.w;
    Bs[lkq + 0][lrow] = b4.x; Bs[lkq + 1][lrow] = b4.y;
    Bs[lkq + 2][lrow] = b4.z; Bs[lkq + 3][lrow] = b4.w;
    __syncthreads();
#pragma unroll
    for (int k = 0; k < 16; ++k) {
      float a[4], b[4];
#pragma unroll
      for (int i = 0; i < 4; ++i) a[i] = As[k][ty * 4 + i];
#pragma unroll
      for (int j = 0; j < 4; ++j) b[j] = Bs[k][tx * 4 + j];
#pragma unroll
      for (int i = 0; i < 4; ++i)
#pragma unroll
        for (int j = 0; j < 4; ++j) acc[i][j] = fmaf(a[i], b[j], acc[i][j]);
    }
    __syncthreads();
  }
#pragma unroll
  for (int i = 0; i < 4; ++i) {
    float4 v;
    v.x = acc[i][0] + bias[bn0 + tx * 4 + 0];
    v.y = acc[i][1] + bias[bn0 + tx * 4 + 1];
    v.z = acc[i][2] + bias[bn0 + tx * 4 + 2];
    v.w = acc[i][3] + bias[bn0 + tx * 4 + 3];
    *(float4*)(C + (size_t)(bm0 + ty * 4 + i) * H_N + bn0 + tx * 4) = v;
  }
}

__global__ __launch_bounds__(256) void gemm_out_kernel(
    const float* __restrict__ hf, const float* __restrict__ hb,
    const float* __restrict__ Wyf, const float* __restrict__ Wyb,
    const float* __restrict__ by, float* __restrict__ y)
{
  const int bm0 = blockIdx.y * 64;   // T dim
  const int bn0 = blockIdx.x * 64;   // OUT dim
  __shared__ float As[16][65];
  __shared__ float Bs[16][65];
  const int tid  = threadIdx.x;
  const int ty   = tid >> 4, tx = tid & 15;
  const int lrow = tid >> 2, lkq = (tid & 3) << 2;
  float acc[4][4] = {};

#pragma unroll 1
  for (int pass = 0; pass < 2; ++pass) {
    const float* __restrict__ A = pass ? hb : hf;
    const float* __restrict__ B = pass ? Wyb : Wyf;
    for (int k0 = 0; k0 < H_N; k0 += 16) {
      float4 a4 = *(const float4*)(A + (size_t)(bm0 + lrow) * H_N + k0 + lkq);
      float4 b4 = *(const float4*)(B + (size_t)(bn0 + lrow) * H_N + k0 + lkq);
      As[lkq + 0][lrow] = a4.x; As[lkq + 1][lrow] = a4.y;
      As[lkq + 2][lrow] = a4.z; As[lkq + 3][lrow] = a4.w;
      Bs[lkq + 0][lrow] = b4.x; Bs[lkq + 1][lrow] = b4.y;
      Bs[lkq + 2][lrow] = b4.z; Bs[lkq + 3][lrow] = b4.w;
      __syncthreads();
#pragma unroll
      for (int k = 0; k < 16; ++k) {
        float a[4], b[4];
#pragma unroll
        for (int i = 0; i < 4; ++i) a[i] = As[k][ty * 4 + i];
#pragma unroll
        for (int j = 0; j < 4; ++j) b[j] = Bs[k][tx * 4 + j];
#pragma unroll
        for (int i = 0; i < 4; ++i)
#pragma unroll
          for (int j = 0; j < 4; ++j) acc[i][j] = fmaf(a[i], b[j], acc[i][j]);
      }
      __syncthreads();
    }
  }
#pragma unroll
  for (int i = 0; i < 4; ++i) {
    float4 v;
    v.x = acc[i][0] + by[bn0 + tx * 4 + 0];
    v.y = acc[i][1] + by[bn0 + tx * 4 + 1];
    v.z = acc[i][2] + by[bn0 + tx * 4 + 2];
    v.w = acc[i][3] + by[bn0 + tx * 4 + 3];
    *(float4*)(y + (size_t)(bm0 + ty * 4 + i) * OUT_N + bn0 + tx * 4) = v;
  }
}

// ---------------------------------------------------------------------------
// Persistent bidirectional recurrence.
// Blocks [0,KD): forward, [KD,2KD): backward. Block owns RPB=32 rows of Wh,
// register-resident (float4 wv[4][8] per lane = 128 VGPRs). Per step:
//   spin on done[prev] == KD  ->  load full h_prev (8KB)  ->  128 FMA/lane
//   -> 64-lane butterfly reduce (4 rows/wave)  -> tanh + store 32 rows
//   -> __syncthreads -> tid0 release-atomicAdd(done[t]).
// Weight layout per lane: wv[q][k] = Wh[row][k*256 + lane*4 .. +3]
// ---------------------------------------------------------------------------
__global__ __launch_bounds__(RTHREADS, 2) void recurrent_kernel(
    const float* __restrict__ Whf, const float* __restrict__ Whb,
    const float* __restrict__ xwf, const float* __restrict__ xwb,
    float* __restrict__ hf, float* __restrict__ hb,
    unsigned* __restrict__ df, unsigned* __restrict__ db)
{
  const int b    = blockIdx.x;
  const bool fwd = (b < KD);
  const int rb   = (fwd ? b : b - KD) * RPB;
  const float* __restrict__ Wh = fwd ? Whf : Whb;
  const float* __restrict__ xw = fwd ? xwf : xwb;
  float* __restrict__ hist     = fwd ? hf : hb;
  unsigned* __restrict__ done  = fwd ? df : db;

  const int w     = threadIdx.x >> 6;
  const int lane  = threadIdx.x & 63;
  const int jbase = lane << 2;          // 0..252

  // Load weight slice into registers (one-time, 256 KB/block).
  float4 wv[4][8];
#pragma unroll
  for (int q = 0; q < 4; ++q)
#pragma unroll
    for (int k = 0; k < 8; ++k)
      wv[q][k] = *(const float4*)(Wh + (size_t)(rb + w * 4 + q) * H_N + k * 256 + jbase);

  for (int s = 0; s < T_N; ++s) {
    const int t  = fwd ? s : (T_N - 1 - s);
    const int pt = fwd ? (t - 1) : (t + 1);

    // Prefetch xw values for our rows (independent of h, overlaps the spin).
    float xwv[4];
    if (lane == 0) {
#pragma unroll
      for (int q = 0; q < 4; ++q)
        xwv[q] = xw[(size_t)t * H_N + rb + w * 4 + q];
    }

    if (s > 0) {
      if (w == 0) {
        while (__hip_atomic_load(done + pt, __ATOMIC_RELAXED,
                                 __HIP_MEMORY_SCOPE_AGENT) < (unsigned)KD) {
          __builtin_amdgcn_s_sleep(1);
        }
        __threadfence();   // agent acquire: make remote h stores visible
      }
      __syncthreads();
    }

    float4 hv[8];
    if (s == 0) {
#pragma unroll
      for (int k = 0; k < 8; ++k) hv[k] = make_float4(0.f, 0.f, 0.f, 0.f);
    } else {
      const float* __restrict__ hp = hist + (size_t)pt * H_N;
#pragma unroll
      for (int k = 0; k < 8; ++k)
        hv[k] = *(const float4*)(hp + k * 256 + jbase);
    }

    float accA[4] = {0.f, 0.f, 0.f, 0.f};
    float accB[4] = {0.f, 0.f, 0.f, 0.f};
#pragma unroll
    for (int q = 0; q < 4; ++q) {
#pragma unroll
      for (int k = 0; k < 8; k += 2) {
        accA[q] = fmaf(wv[q][k].x, hv[k].x, accA[q]);
        accA[q] = fmaf(wv[q][k].y, hv[k].y, accA[q]);
        accA[q] = fmaf(wv[q][k].z, hv[k].z, accA[q]);
        accA[q] = fmaf(wv[q][k].w, hv[k].w, accA[q]);
        accB[q] = fmaf(wv[q][k + 1].x, hv[k + 1].x, accB[q]);
        accB[q] = fmaf(wv[q][k + 1].y, hv[k + 1].y, accB[q]);
        accB[q] = fmaf(wv[q][k + 1].z, hv[k + 1].z, accB[q]);
        accB[q] = fmaf(wv[q][k + 1].w, hv[k + 1].w, accB[q]);
      }
    }
    float acc[4];
#pragma unroll
    for (int q = 0; q < 4; ++q) {
      acc[q] = accA[q] + accB[q];
#pragma unroll
      for (int off = 32; off > 0; off >>= 1)
        acc[q] += __shfl_xor(acc[q], off, 64);
    }

    if (lane == 0) {
#pragma unroll
      for (int q = 0; q < 4; ++q)
        hist[(size_t)t * H_N + rb + w * 4 + q] = tanhf(acc[q] + xwv[q]);
    }

    __syncthreads();   // drains vmcnt: all 32 row-stores complete
    if (threadIdx.x == 0)
      __hip_atomic_fetch_add(done + t, 1u, __ATOMIC_RELEASE,
                             __HIP_MEMORY_SCOPE_AGENT);
  }
}

extern "C" void kernel_launch(void* const* d_in, const int* in_sizes, int n_in,
                              void* d_out, int out_size, void* d_ws, size_t ws_size,
                              hipStream_t stream) {
  const float* x   = (const float*)d_in[0];
  const float* Wxf = (const float*)d_in[1];
  const float* Whf = (const float*)d_in[2];
  const float* bhf = (const float*)d_in[3];
  const float* Wxb = (const float*)d_in[4];
  const float* Whb = (const float*)d_in[5];
  const float* bhb = (const float*)d_in[6];
  const float* Wyf = (const float*)d_in[7];
  const float* Wyb = (const float*)d_in[8];
  const float* by  = (const float*)d_in[9];
  float* y = (float*)d_out;

  char* ws = (char*)d_ws;
  float* xwf   = (float*)(ws + XW_F_OFF);
  float* xwb   = (float*)(ws + XW_B_OFF);
  float* hf    = (float*)(ws + HF_OFF);
  float* hb    = (float*)(ws + HB_OFF);
  unsigned* df = (unsigned*)(ws + DF_OFF);
  unsigned* db = (unsigned*)(ws + DB_OFF);

  hipLaunchKernelGGL(init_flags_kernel, dim3(17), dim3(256), 0, stream, df, db);
  hipLaunchKernelGGL(gemm_xw_kernel, dim3(H_N / 64, T_N / 64, 2), dim3(256), 0, stream,
                     x, Wxf, bhf, Wxb, bhb, xwf, xwb);
  hipLaunchKernelGGL(recurrent_kernel, dim3(2 * KD), dim3(RTHREADS), 0, stream,
                     Whf, Whb, xwf, xwb, hf, hb, df, db);
  hipLaunchKernelGGL(gemm_out_kernel, dim3(OUT_N / 64, T_N / 64), dim3(256), 0, stream,
                     hf, hb, Wyf, Wyb, by, y);
}

// Round 3
// 28645.090 us; speedup vs baseline: 1.0385x; 1.0385x over previous
//
#include <hip/hip_runtime.h>
#include <hip/hip_bf16.h>
#include <math.h>

// Problem dims
#define T_N   4096
#define IN_N  1024
#define H_N   2048
#define OUT_N 1024

// Recurrence decomposition: KD3 blocks per direction, each owns RPB3 rows of Wh.
#define KD3  64
#define RPB3 32        // H_N / KD3
#define RTH3 1024      // 16 waves, 2 rows per wave

// Workspace byte offsets (total 128 MiB + 512 B — under round-1-proven ws_size)
#define XW_F_OFF 0ull
#define XW_B_OFF 33554432ull
#define HF_OFF   67108864ull
#define HB_OFF   100663296ull
#define PROG_OFF 134217728ull    // progf: 64 u32 @ +0, progb: 64 u32 @ +256B

__global__ __launch_bounds__(128) void init_prog_kernel(unsigned* __restrict__ p) {
  p[threadIdx.x] = 0u;   // resets both directions' counters (128 words)
}

// ---------------------------------------------------------------------------
// Tiled fp32 NT GEMM: C[m][n] = sum_k A[m][k]*B[n][k] + bias[n]
// 64x64 tile, BK=16, 256 threads, 4x4 per thread.
// ---------------------------------------------------------------------------
__global__ __launch_bounds__(256) void gemm_xw_kernel(
    const float* __restrict__ x,
    const float* __restrict__ Wxf, const float* __restrict__ bhf,
    const float* __restrict__ Wxb, const float* __restrict__ bhb,
    float* __restrict__ xwf, float* __restrict__ xwb)
{
  const int dir = blockIdx.z;
  const float* __restrict__ B    = dir ? Wxb : Wxf;
  const float* __restrict__ bias = dir ? bhb : bhf;
  float* __restrict__ C          = dir ? xwb : xwf;
  const int bm0 = blockIdx.y * 64;   // T dim
  const int bn0 = blockIdx.x * 64;   // H dim

  __shared__ float As[16][65];
  __shared__ float Bs[16][65];
  const int tid  = threadIdx.x;
  const int ty   = tid >> 4, tx = tid & 15;
  const int lrow = tid >> 2, lkq = (tid & 3) << 2;
  float acc[4][4] = {};

  for (int k0 = 0; k0 < IN_N; k0 += 16) {
    float4 a4 = *(const float4*)(x + (size_t)(bm0 + lrow) * IN_N + k0 + lkq);
    float4 b4 = *(const float4*)(B + (size_t)(bn0 + lrow) * IN_N + k0 + lkq);
    As[lkq + 0][lrow] = a4.x; As[lkq + 1][lrow] = a4.y;
    As[lkq + 2][lrow] = a4.z; As[lkq + 3][lrow] = a4.w;
    Bs[lkq + 0][lrow] = b4.x; Bs[lkq + 1][lrow] = b4.y;
    Bs[lkq + 2][lrow] = b4.z; Bs[lkq + 3][lrow] = b4.w;
    __syncthreads();
#pragma unroll
    for (int k = 0; k < 16; ++k) {
      float a[4], b[4];
#pragma unroll
      for (int i = 0; i < 4; ++i) a[i] = As[k][ty * 4 + i];
#pragma unroll
      for (int j = 0; j < 4; ++j) b[j] = Bs[k][tx * 4 + j];
#pragma unroll
      for (int i = 0; i < 4; ++i)
#pragma unroll
        for (int j = 0; j < 4; ++j) acc[i][j] = fmaf(a[i], b[j], acc[i][j]);
    }
    __syncthreads();
  }
#pragma unroll
  for (int i = 0; i < 4; ++i) {
    float4 v;
    v.x = acc[i][0] + bias[bn0 + tx * 4 + 0];
    v.y = acc[i][1] + bias[bn0 + tx * 4 + 1];
    v.z = acc[i][2] + bias[bn0 + tx * 4 + 2];
    v.w = acc[i][3] + bias[bn0 + tx * 4 + 3];
    *(float4*)(C + (size_t)(bm0 + ty * 4 + i) * H_N + bn0 + tx * 4) = v;
  }
}

__global__ __launch_bounds__(256) void gemm_out_kernel(
    const float* __restrict__ hf, const float* __restrict__ hb,
    const float* __restrict__ Wyf, const float* __restrict__ Wyb,
    const float* __restrict__ by, float* __restrict__ y)
{
  const int bm0 = blockIdx.y * 64;   // T dim
  const int bn0 = blockIdx.x * 64;   // OUT dim
  __shared__ float As[16][65];
  __shared__ float Bs[16][65];
  const int tid  = threadIdx.x;
  const int ty   = tid >> 4, tx = tid & 15;
  const int lrow = tid >> 2, lkq = (tid & 3) << 2;
  float acc[4][4] = {};

#pragma unroll 1
  for (int pass = 0; pass < 2; ++pass) {
    const float* __restrict__ A = pass ? hb : hf;
    const float* __restrict__ B = pass ? Wyb : Wyf;
    for (int k0 = 0; k0 < H_N; k0 += 16) {
      float4 a4 = *(const float4*)(A + (size_t)(bm0 + lrow) * H_N + k0 + lkq);
      float4 b4 = *(const float4*)(B + (size_t)(bn0 + lrow) * H_N + k0 + lkq);
      As[lkq + 0][lrow] = a4.x; As[lkq + 1][lrow] = a4.y;
      As[lkq + 2][lrow] = a4.z; As[lkq + 3][lrow] = a4.w;
      Bs[lkq + 0][lrow] = b4.x; Bs[lkq + 1][lrow] = b4.y;
      Bs[lkq + 2][lrow] = b4.z; Bs[lkq + 3][lrow] = b4.w;
      __syncthreads();
#pragma unroll
      for (int k = 0; k < 16; ++k) {
        float a[4], b[4];
#pragma unroll
        for (int i = 0; i < 4; ++i) a[i] = As[k][ty * 4 + i];
#pragma unroll
        for (int j = 0; j < 4; ++j) b[j] = Bs[k][tx * 4 + j];
#pragma unroll
        for (int i = 0; i < 4; ++i)
#pragma unroll
          for (int j = 0; j < 4; ++j) acc[i][j] = fmaf(a[i], b[j], acc[i][j]);
      }
      __syncthreads();
    }
  }
#pragma unroll
  for (int i = 0; i < 4; ++i) {
    float4 v;
    v.x = acc[i][0] + by[bn0 + tx * 4 + 0];
    v.y = acc[i][1] + by[bn0 + tx * 4 + 1];
    v.z = acc[i][2] + by[bn0 + tx * 4 + 2];
    v.w = acc[i][3] + by[bn0 + tx * 4 + 3];
    *(float4*)(y + (size_t)(bm0 + ty * 4 + i) * OUT_N + bn0 + tx * 4) = v;
  }
}

// ---------------------------------------------------------------------------
// Persistent bidirectional recurrence, v3.
// 128 blocks (64/dir — half the CUs, co-residency guaranteed), 1024 threads.
// Block owns RPB3=32 rows; 16 waves x 2 rows. Weights register-resident:
// wv[2][8] float4 = 64 VGPRs/lane. Monotonic per-block progress counters
// (64 words/dir): wave0 lane i polls prog[i] until __all(p >= s).
// Per step: poll -> acquire fence -> stage h_prev to LDS (float2/thread)
// -> 8x ds_read_b128 + 64 FMA/lane -> 64-lane butterfly x2 -> lane0 stores
// 2 rows + tanh -> __syncthreads -> tid0 release-stores prog[bb] = s+1.
// ---------------------------------------------------------------------------
__global__ __launch_bounds__(RTH3, 4) void recurrent_kernel(
    const float* __restrict__ Whf, const float* __restrict__ Whb,
    const float* __restrict__ xwf, const float* __restrict__ xwb,
    float* __restrict__ hf, float* __restrict__ hb,
    unsigned* __restrict__ progf, unsigned* __restrict__ progb)
{
  const int b    = blockIdx.x;
  const bool fwd = (b < KD3);
  const int bb   = fwd ? b : b - KD3;
  const int rb   = bb * RPB3;
  const float* __restrict__ Wh = fwd ? Whf : Whb;
  const float* __restrict__ xw = fwd ? xwf : xwb;
  float* __restrict__ hist     = fwd ? hf : hb;
  unsigned* __restrict__ prog  = fwd ? progf : progb;

  const int w     = threadIdx.x >> 6;   // wave 0..15
  const int lane  = threadIdx.x & 63;
  const int jbase = lane << 2;          // 0..252
  const int r0    = rb + 2 * w;         // this wave's two rows

  __shared__ float hs[H_N];             // 8 KB staged h_prev

  // One-time: weight slice into registers (64 VGPRs/lane).
  float4 wv[2][8];
#pragma unroll
  for (int q = 0; q < 2; ++q)
#pragma unroll
    for (int k = 0; k < 8; ++k)
      wv[q][k] = *(const float4*)(Wh + (size_t)(r0 + q) * H_N + k * 256 + jbase);

  for (int s = 0; s < T_N; ++s) {
    const int t  = fwd ? s : (T_N - 1 - s);
    const int pt = fwd ? (t - 1) : (t + 1);

    // xw prefetch for our two rows (independent of h; overlaps the poll).
    float xwv0 = 0.f, xwv1 = 0.f;
    if (lane == 0) {
      xwv0 = xw[(size_t)t * H_N + r0 + 0];
      xwv1 = xw[(size_t)t * H_N + r0 + 1];
    }

    if (s > 0) {
      if (w == 0) {
        for (;;) {
          unsigned p = __hip_atomic_load(prog + lane, __ATOMIC_RELAXED,
                                         __HIP_MEMORY_SCOPE_AGENT);
          if (__all(p >= (unsigned)s)) break;
          __builtin_amdgcn_s_sleep(1);
        }
        __threadfence();   // agent acquire: make remote h stores visible
      }
      __syncthreads();
      // Cooperative stage: 1024 threads x float2 = 2048 floats.
      *(float2*)(hs + (threadIdx.x << 1)) =
          *(const float2*)(hist + (size_t)pt * H_N + (threadIdx.x << 1));
      __syncthreads();
    } else {
      *(float2*)(hs + (threadIdx.x << 1)) = make_float2(0.f, 0.f);
      __syncthreads();
    }

    // LDS fragments: conflict-free ds_read_b128 (lane-consecutive 16B).
    float acc0 = 0.f, acc1 = 0.f;
#pragma unroll
    for (int k = 0; k < 8; ++k) {
      float4 h4 = *(const float4*)(hs + k * 256 + jbase);
      acc0 = fmaf(wv[0][k].x, h4.x, acc0);
      acc0 = fmaf(wv[0][k].y, h4.y, acc0);
      acc0 = fmaf(wv[0][k].z, h4.z, acc0);
      acc0 = fmaf(wv[0][k].w, h4.w, acc0);
      acc1 = fmaf(wv[1][k].x, h4.x, acc1);
      acc1 = fmaf(wv[1][k].y, h4.y, acc1);
      acc1 = fmaf(wv[1][k].z, h4.z, acc1);
      acc1 = fmaf(wv[1][k].w, h4.w, acc1);
    }
#pragma unroll
    for (int off = 32; off > 0; off >>= 1) {
      acc0 += __shfl_xor(acc0, off, 64);
      acc1 += __shfl_xor(acc1, off, 64);
    }

    if (lane == 0) {
      hist[(size_t)t * H_N + r0 + 0] = tanhf(acc0 + xwv0);
      hist[(size_t)t * H_N + r0 + 1] = tanhf(acc1 + xwv1);
    }

    __syncthreads();   // per-wave vmcnt drain: all 32 row-stores complete
    if (threadIdx.x == 0)
      __hip_atomic_store(prog + bb, (unsigned)(s + 1), __ATOMIC_RELEASE,
                         __HIP_MEMORY_SCOPE_AGENT);
  }
}

extern "C" void kernel_launch(void* const* d_in, const int* in_sizes, int n_in,
                              void* d_out, int out_size, void* d_ws, size_t ws_size,
                              hipStream_t stream) {
  const float* x   = (const float*)d_in[0];
  const float* Wxf = (const float*)d_in[1];
  const float* Whf = (const float*)d_in[2];
  const float* bhf = (const float*)d_in[3];
  const float* Wxb = (const float*)d_in[4];
  const float* Whb = (const float*)d_in[5];
  const float* bhb = (const float*)d_in[6];
  const float* Wyf = (const float*)d_in[7];
  const float* Wyb = (const float*)d_in[8];
  const float* by  = (const float*)d_in[9];
  float* y = (float*)d_out;

  char* ws = (char*)d_ws;
  float* xwf      = (float*)(ws + XW_F_OFF);
  float* xwb      = (float*)(ws + XW_B_OFF);
  float* hf       = (float*)(ws + HF_OFF);
  float* hb       = (float*)(ws + HB_OFF);
  unsigned* progf = (unsigned*)(ws + PROG_OFF);
  unsigned* progb = progf + 64;   // +256 B, separate cache line

  hipLaunchKernelGGL(init_prog_kernel, dim3(1), dim3(128), 0, stream, progf);
  hipLaunchKernelGGL(gemm_xw_kernel, dim3(H_N / 64, T_N / 64, 2), dim3(256), 0, stream,
                     x, Wxf, bhf, Wxb, bhb, xwf, xwb);
  hipLaunchKernelGGL(recurrent_kernel, dim3(2 * KD3), dim3(RTH3), 0, stream,
                     Whf, Whb, xwf, xwb, hf, hb, progf, progb);
  hipLaunchKernelGGL(gemm_out_kernel, dim3(OUT_N / 64, T_N / 64), dim3(256), 0, stream,
                     hf, hb, Wyf, Wyb, by, y);
}

// Round 4
// 25903.574 us; speedup vs baseline: 1.1485x; 1.1058x over previous
//
#include <hip/hip_runtime.h>
#include <hip/hip_bf16.h>
#include <math.h>

// Problem dims
#define T_N   4096
#define IN_N  1024
#define H_N   2048
#define OUT_N 1024

// Recurrence decomposition: KD3 blocks per direction, each owns RPB3 rows of Wh.
#define KD3  64
#define RPB3 32        // H_N / KD3
#define RTH3 1024      // 16 waves, 2 rows per wave

// Workspace byte offsets (total 128 MiB + 512 B)
#define XW_F_OFF 0ull
#define XW_B_OFF 33554432ull
#define HF_OFF   67108864ull
#define HB_OFF   100663296ull
#define PROG_OFF 134217728ull    // progf: 64 u32 @ +0, progb: 64 u32 @ +256B

__global__ __launch_bounds__(128) void init_prog_kernel(unsigned* __restrict__ p) {
  p[threadIdx.x] = 0u;   // resets both directions' counters (128 words)
}

// ---------------------------------------------------------------------------
// Tiled fp32 NT GEMM: C[m][n] = sum_k A[m][k]*B[n][k] + bias[n]
// 64x64 tile, BK=16, 256 threads, 4x4 per thread.
// ---------------------------------------------------------------------------
__global__ __launch_bounds__(256) void gemm_xw_kernel(
    const float* __restrict__ x,
    const float* __restrict__ Wxf, const float* __restrict__ bhf,
    const float* __restrict__ Wxb, const float* __restrict__ bhb,
    float* __restrict__ xwf, float* __restrict__ xwb)
{
  const int dir = blockIdx.z;
  const float* __restrict__ B    = dir ? Wxb : Wxf;
  const float* __restrict__ bias = dir ? bhb : bhf;
  float* __restrict__ C          = dir ? xwb : xwf;
  const int bm0 = blockIdx.y * 64;   // T dim
  const int bn0 = blockIdx.x * 64;   // H dim

  __shared__ float As[16][65];
  __shared__ float Bs[16][65];
  const int tid  = threadIdx.x;
  const int ty   = tid >> 4, tx = tid & 15;
  const int lrow = tid >> 2, lkq = (tid & 3) << 2;
  float acc[4][4] = {};

  for (int k0 = 0; k0 < IN_N; k0 += 16) {
    float4 a4 = *(const float4*)(x + (size_t)(bm0 + lrow) * IN_N + k0 + lkq);
    float4 b4 = *(const float4*)(B + (size_t)(bn0 + lrow) * IN_N + k0 + lkq);
    As[lkq + 0][lrow] = a4.x; As[lkq + 1][lrow] = a4.y;
    As[lkq + 2][lrow] = a4.z; As[lkq + 3][lrow] = a4.w;
    Bs[lkq + 0][lrow] = b4.x; Bs[lkq + 1][lrow] = b4.y;
    Bs[lkq + 2][lrow] = b4.z; Bs[lkq + 3][lrow] = b4.w;
    __syncthreads();
#pragma unroll
    for (int k = 0; k < 16; ++k) {
      float a[4], b[4];
#pragma unroll
      for (int i = 0; i < 4; ++i) a[i] = As[k][ty * 4 + i];
#pragma unroll
      for (int j = 0; j < 4; ++j) b[j] = Bs[k][tx * 4 + j];
#pragma unroll
      for (int i = 0; i < 4; ++i)
#pragma unroll
        for (int j = 0; j < 4; ++j) acc[i][j] = fmaf(a[i], b[j], acc[i][j]);
    }
    __syncthreads();
  }
#pragma unroll
  for (int i = 0; i < 4; ++i) {
    float4 v;
    v.x = acc[i][0] + bias[bn0 + tx * 4 + 0];
    v.y = acc[i][1] + bias[bn0 + tx * 4 + 1];
    v.z = acc[i][2] + bias[bn0 + tx * 4 + 2];
    v.w = acc[i][3] + bias[bn0 + tx * 4 + 3];
    *(float4*)(C + (size_t)(bm0 + ty * 4 + i) * H_N + bn0 + tx * 4) = v;
  }
}

__global__ __launch_bounds__(256) void gemm_out_kernel(
    const float* __restrict__ hf, const float* __restrict__ hb,
    const float* __restrict__ Wyf, const float* __restrict__ Wyb,
    const float* __restrict__ by, float* __restrict__ y)
{
  const int bm0 = blockIdx.y * 64;   // T dim
  const int bn0 = blockIdx.x * 64;   // OUT dim
  __shared__ float As[16][65];
  __shared__ float Bs[16][65];
  const int tid  = threadIdx.x;
  const int ty   = tid >> 4, tx = tid & 15;
  const int lrow = tid >> 2, lkq = (tid & 3) << 2;
  float acc[4][4] = {};

#pragma unroll 1
  for (int pass = 0; pass < 2; ++pass) {
    const float* __restrict__ A = pass ? hb : hf;
    const float* __restrict__ B = pass ? Wyb : Wyf;
    for (int k0 = 0; k0 < H_N; k0 += 16) {
      float4 a4 = *(const float4*)(A + (size_t)(bm0 + lrow) * H_N + k0 + lkq);
      float4 b4 = *(const float4*)(B + (size_t)(bn0 + lrow) * H_N + k0 + lkq);
      As[lkq + 0][lrow] = a4.x; As[lkq + 1][lrow] = a4.y;
      As[lkq + 2][lrow] = a4.z; As[lkq + 3][lrow] = a4.w;
      Bs[lkq + 0][lrow] = b4.x; Bs[lkq + 1][lrow] = b4.y;
      Bs[lkq + 2][lrow] = b4.z; Bs[lkq + 3][lrow] = b4.w;
      __syncthreads();
#pragma unroll
      for (int k = 0; k < 16; ++k) {
        float a[4], b[4];
#pragma unroll
        for (int i = 0; i < 4; ++i) a[i] = As[k][ty * 4 + i];
#pragma unroll
        for (int j = 0; j < 4; ++j) b[j] = Bs[k][tx * 4 + j];
#pragma unroll
        for (int i = 0; i < 4; ++i)
#pragma unroll
          for (int j = 0; j < 4; ++j) acc[i][j] = fmaf(a[i], b[j], acc[i][j]);
      }
      __syncthreads();
    }
  }
#pragma unroll
  for (int i = 0; i < 4; ++i) {
    float4 v;
    v.x = acc[i][0] + by[bn0 + tx * 4 + 0];
    v.y = acc[i][1] + by[bn0 + tx * 4 + 1];
    v.z = acc[i][2] + by[bn0 + tx * 4 + 2];
    v.w = acc[i][3] + by[bn0 + tx * 4 + 3];
    *(float4*)(y + (size_t)(bm0 + ty * 4 + i) * OUT_N + bn0 + tx * 4) = v;
  }
}

// ---------------------------------------------------------------------------
// Persistent bidirectional recurrence, v4.
// Identical to v3 except: after the one-time weight load, every wv component
// is pinned with an empty asm volatile "+v" — the compiler may no longer
// rematerialize the loads inside the timestep loop (v3 evidence: VGPR=52,
// i.e. 256 KB/block of weights re-streamed from L2/LLC every step = the
// dominant cost). With pinning, weights stay in 64 VGPRs/lane for all 4096
// steps; per-step cost collapses to sync latency + h round-trip + compute.
// ---------------------------------------------------------------------------
__global__ __launch_bounds__(RTH3, 4) void recurrent_kernel(
    const float* __restrict__ Whf, const float* __restrict__ Whb,
    const float* __restrict__ xwf, const float* __restrict__ xwb,
    float* __restrict__ hf, float* __restrict__ hb,
    unsigned* __restrict__ progf, unsigned* __restrict__ progb)
{
  const int b    = blockIdx.x;
  const bool fwd = (b < KD3);
  const int bb   = fwd ? b : b - KD3;
  const int rb   = bb * RPB3;
  const float* __restrict__ Wh = fwd ? Whf : Whb;
  const float* __restrict__ xw = fwd ? xwf : xwb;
  float* __restrict__ hist     = fwd ? hf : hb;
  unsigned* __restrict__ prog  = fwd ? progf : progb;

  const int w     = threadIdx.x >> 6;   // wave 0..15
  const int lane  = threadIdx.x & 63;
  const int jbase = lane << 2;          // 0..252
  const int r0    = rb + 2 * w;         // this wave's two rows

  __shared__ float hs[H_N];             // 8 KB staged h_prev

  // One-time: weight slice into registers (64 VGPRs/lane), then PIN so the
  // compiler cannot sink the loads into the loop.
  float4 wv[2][8];
#pragma unroll
  for (int q = 0; q < 2; ++q)
#pragma unroll
    for (int k = 0; k < 8; ++k)
      wv[q][k] = *(const float4*)(Wh + (size_t)(r0 + q) * H_N + k * 256 + jbase);
#pragma unroll
  for (int q = 0; q < 2; ++q)
#pragma unroll
    for (int k = 0; k < 8; ++k)
      asm volatile("" : "+v"(wv[q][k].x), "+v"(wv[q][k].y),
                        "+v"(wv[q][k].z), "+v"(wv[q][k].w));

  for (int s = 0; s < T_N; ++s) {
    const int t  = fwd ? s : (T_N - 1 - s);
    const int pt = fwd ? (t - 1) : (t + 1);

    // xw prefetch for our two rows (independent of h; overlaps the poll).
    float xwv0 = 0.f, xwv1 = 0.f;
    if (lane == 0) {
      xwv0 = xw[(size_t)t * H_N + r0 + 0];
      xwv1 = xw[(size_t)t * H_N + r0 + 1];
    }

    if (s > 0) {
      if (w == 0) {
        for (;;) {
          unsigned p = __hip_atomic_load(prog + lane, __ATOMIC_RELAXED,
                                         __HIP_MEMORY_SCOPE_AGENT);
          if (__all(p >= (unsigned)s)) break;
          __builtin_amdgcn_s_sleep(1);
        }
        __threadfence();   // agent acquire: make remote h stores visible
      }
      __syncthreads();
      // Cooperative stage: 1024 threads x float2 = 2048 floats.
      *(float2*)(hs + (threadIdx.x << 1)) =
          *(const float2*)(hist + (size_t)pt * H_N + (threadIdx.x << 1));
      __syncthreads();
    } else {
      *(float2*)(hs + (threadIdx.x << 1)) = make_float2(0.f, 0.f);
      __syncthreads();
    }

    // LDS fragments: conflict-free ds_read_b128 (lane-consecutive 16B).
    float acc0 = 0.f, acc1 = 0.f;
#pragma unroll
    for (int k = 0; k < 8; ++k) {
      float4 h4 = *(const float4*)(hs + k * 256 + jbase);
      acc0 = fmaf(wv[0][k].x, h4.x, acc0);
      acc0 = fmaf(wv[0][k].y, h4.y, acc0);
      acc0 = fmaf(wv[0][k].z, h4.z, acc0);
      acc0 = fmaf(wv[0][k].w, h4.w, acc0);
      acc1 = fmaf(wv[1][k].x, h4.x, acc1);
      acc1 = fmaf(wv[1][k].y, h4.y, acc1);
      acc1 = fmaf(wv[1][k].z, h4.z, acc1);
      acc1 = fmaf(wv[1][k].w, h4.w, acc1);
    }
#pragma unroll
    for (int off = 32; off > 0; off >>= 1) {
      acc0 += __shfl_xor(acc0, off, 64);
      acc1 += __shfl_xor(acc1, off, 64);
    }

    if (lane == 0) {
      hist[(size_t)t * H_N + r0 + 0] = tanhf(acc0 + xwv0);
      hist[(size_t)t * H_N + r0 + 1] = tanhf(acc1 + xwv1);
    }

    __syncthreads();   // per-wave vmcnt drain: all 32 row-stores complete
    if (threadIdx.x == 0)
      __hip_atomic_store(prog + bb, (unsigned)(s + 1), __ATOMIC_RELEASE,
                         __HIP_MEMORY_SCOPE_AGENT);
  }
}

extern "C" void kernel_launch(void* const* d_in, const int* in_sizes, int n_in,
                              void* d_out, int out_size, void* d_ws, size_t ws_size,
                              hipStream_t stream) {
  const float* x   = (const float*)d_in[0];
  const float* Wxf = (const float*)d_in[1];
  const float* Whf = (const float*)d_in[2];
  const float* bhf = (const float*)d_in[3];
  const float* Wxb = (const float*)d_in[4];
  const float* Whb = (const float*)d_in[5];
  const float* bhb = (const float*)d_in[6];
  const float* Wyf = (const float*)d_in[7];
  const float* Wyb = (const float*)d_in[8];
  const float* by  = (const float*)d_in[9];
  float* y = (float*)d_out;

  char* ws = (char*)d_ws;
  float* xwf      = (float*)(ws + XW_F_OFF);
  float* xwb      = (float*)(ws + XW_B_OFF);
  float* hf       = (float*)(ws + HF_OFF);
  float* hb       = (float*)(ws + HB_OFF);
  unsigned* progf = (unsigned*)(ws + PROG_OFF);
  unsigned* progb = progf + 64;   // +256 B, separate cache line

  hipLaunchKernelGGL(init_prog_kernel, dim3(1), dim3(128), 0, stream, progf);
  hipLaunchKernelGGL(gemm_xw_kernel, dim3(H_N / 64, T_N / 64, 2), dim3(256), 0, stream,
                     x, Wxf, bhf, Wxb, bhb, xwf, xwb);
  hipLaunchKernelGGL(recurrent_kernel, dim3(2 * KD3), dim3(RTH3), 0, stream,
                     Whf, Whb, xwf, xwb, hf, hb, progf, progb);
  hipLaunchKernelGGL(gemm_out_kernel, dim3(OUT_N / 64, T_N / 64), dim3(256), 0, stream,
                     hf, hb, Wyf, Wyb, by, y);
}

// Round 5
// 12455.531 us; speedup vs baseline: 2.3884x; 2.0797x over previous
//
#include <hip/hip_runtime.h>
#include <hip/hip_bf16.h>
#include <math.h>

// Problem dims
#define T_N   4096
#define IN_N  1024
#define H_N   2048
#define OUT_N 1024

// Recurrence decomposition: KD3 blocks per direction, each owns RPB3 rows of Wh.
#define KD3  64
#define RPB3 32        // H_N / KD3
#define RTH3 1024      // 16 waves, 2 rows per wave

// Workspace byte offsets (total 128 MiB + 512 B)
#define XW_F_OFF 0ull
#define XW_B_OFF 33554432ull
#define HF_OFF   67108864ull
#define HB_OFF   100663296ull
#define PROG_OFF 134217728ull    // progf: 64 u32 @ +0, progb: 64 u32 @ +256B

__global__ __launch_bounds__(128) void init_prog_kernel(unsigned* __restrict__ p) {
  p[threadIdx.x] = 0u;   // resets both directions' counters (128 words)
}

// ---------------------------------------------------------------------------
// Tiled fp32 NT GEMM: C[m][n] = sum_k A[m][k]*B[n][k] + bias[n]
// 64x64 tile, BK=16, 256 threads, 4x4 per thread.
// ---------------------------------------------------------------------------
__global__ __launch_bounds__(256) void gemm_xw_kernel(
    const float* __restrict__ x,
    const float* __restrict__ Wxf, const float* __restrict__ bhf,
    const float* __restrict__ Wxb, const float* __restrict__ bhb,
    float* __restrict__ xwf, float* __restrict__ xwb)
{
  const int dir = blockIdx.z;
  const float* __restrict__ B    = dir ? Wxb : Wxf;
  const float* __restrict__ bias = dir ? bhb : bhf;
  float* __restrict__ C          = dir ? xwb : xwf;
  const int bm0 = blockIdx.y * 64;   // T dim
  const int bn0 = blockIdx.x * 64;   // H dim

  __shared__ float As[16][65];
  __shared__ float Bs[16][65];
  const int tid  = threadIdx.x;
  const int ty   = tid >> 4, tx = tid & 15;
  const int lrow = tid >> 2, lkq = (tid & 3) << 2;
  float acc[4][4] = {};

  for (int k0 = 0; k0 < IN_N; k0 += 16) {
    float4 a4 = *(const float4*)(x + (size_t)(bm0 + lrow) * IN_N + k0 + lkq);
    float4 b4 = *(const float4*)(B + (size_t)(bn0 + lrow) * IN_N + k0 + lkq);
    As[lkq + 0][lrow] = a4.x; As[lkq + 1][lrow] = a4.y;
    As[lkq + 2][lrow] = a4.z; As[lkq + 3][lrow] = a4.w;
    Bs[lkq + 0][lrow] = b4.x; Bs[lkq + 1][lrow] = b4.y;
    Bs[lkq + 2][lrow] = b4.z; Bs[lkq + 3][lrow] = b4.w;
    __syncthreads();
#pragma unroll
    for (int k = 0; k < 16; ++k) {
      float a[4], b[4];
#pragma unroll
      for (int i = 0; i < 4; ++i) a[i] = As[k][ty * 4 + i];
#pragma unroll
      for (int j = 0; j < 4; ++j) b[j] = Bs[k][tx * 4 + j];
#pragma unroll
      for (int i = 0; i < 4; ++i)
#pragma unroll
        for (int j = 0; j < 4; ++j) acc[i][j] = fmaf(a[i], b[j], acc[i][j]);
    }
    __syncthreads();
  }
#pragma unroll
  for (int i = 0; i < 4; ++i) {
    float4 v;
    v.x = acc[i][0] + bias[bn0 + tx * 4 + 0];
    v.y = acc[i][1] + bias[bn0 + tx * 4 + 1];
    v.z = acc[i][2] + bias[bn0 + tx * 4 + 2];
    v.w = acc[i][3] + bias[bn0 + tx * 4 + 3];
    *(float4*)(C + (size_t)(bm0 + ty * 4 + i) * H_N + bn0 + tx * 4) = v;
  }
}

__global__ __launch_bounds__(256) void gemm_out_kernel(
    const float* __restrict__ hf, const float* __restrict__ hb,
    const float* __restrict__ Wyf, const float* __restrict__ Wyb,
    const float* __restrict__ by, float* __restrict__ y)
{
  const int bm0 = blockIdx.y * 64;   // T dim
  const int bn0 = blockIdx.x * 64;   // OUT dim
  __shared__ float As[16][65];
  __shared__ float Bs[16][65];
  const int tid  = threadIdx.x;
  const int ty   = tid >> 4, tx = tid & 15;
  const int lrow = tid >> 2, lkq = (tid & 3) << 2;
  float acc[4][4] = {};

#pragma unroll 1
  for (int pass = 0; pass < 2; ++pass) {
    const float* __restrict__ A = pass ? hb : hf;
    const float* __restrict__ B = pass ? Wyb : Wyf;
    for (int k0 = 0; k0 < H_N; k0 += 16) {
      float4 a4 = *(const float4*)(A + (size_t)(bm0 + lrow) * H_N + k0 + lkq);
      float4 b4 = *(const float4*)(B + (size_t)(bn0 + lrow) * H_N + k0 + lkq);
      As[lkq + 0][lrow] = a4.x; As[lkq + 1][lrow] = a4.y;
      As[lkq + 2][lrow] = a4.z; As[lkq + 3][lrow] = a4.w;
      Bs[lkq + 0][lrow] = b4.x; Bs[lkq + 1][lrow] = b4.y;
      Bs[lkq + 2][lrow] = b4.z; Bs[lkq + 3][lrow] = b4.w;
      __syncthreads();
#pragma unroll
      for (int k = 0; k < 16; ++k) {
        float a[4], b[4];
#pragma unroll
        for (int i = 0; i < 4; ++i) a[i] = As[k][ty * 4 + i];
#pragma unroll
        for (int j = 0; j < 4; ++j) b[j] = Bs[k][tx * 4 + j];
#pragma unroll
        for (int i = 0; i < 4; ++i)
#pragma unroll
          for (int j = 0; j < 4; ++j) acc[i][j] = fmaf(a[i], b[j], acc[i][j]);
      }
      __syncthreads();
    }
  }
#pragma unroll
  for (int i = 0; i < 4; ++i) {
    float4 v;
    v.x = acc[i][0] + by[bn0 + tx * 4 + 0];
    v.y = acc[i][1] + by[bn0 + tx * 4 + 1];
    v.z = acc[i][2] + by[bn0 + tx * 4 + 2];
    v.w = acc[i][3] + by[bn0 + tx * 4 + 3];
    *(float4*)(y + (size_t)(bm0 + ty * 4 + i) * OUT_N + bn0 + tx * 4) = v;
  }
}

// ---------------------------------------------------------------------------
// Persistent bidirectional recurrence, v5 — FENCELESS.
// All cross-block exchange (h rows + progress flags) goes through agent-scope
// RELAXED atomics, which lower to L1/L2-bypassing LLC accesses (sc1). Nothing
// on the h path is ever dirty in an L2, so no buffer_wbl2 is needed; nothing
// can be stale in L1/L2, so no buffer_inv is needed. Ordering:
//   producer: h atomic-stores -> __syncthreads (compiler emits s_waitcnt
//             vmcnt(0) per wave before s_barrier => stores ACKed at LLC)
//             -> thread0 relaxed flag store  (de-facto release)
//   consumer: wave0 polls relaxed flags -> __syncthreads -> 64-bit relaxed
//             atomic staging loads (issue strictly after poll; LLC-sourced)
// v4 evidence for this: fences were the only untouched serial cost; weight
// pinning (on-chip residency) bought just 6%.
// ---------------------------------------------------------------------------
__global__ __launch_bounds__(RTH3, 4) void recurrent_kernel(
    const float* __restrict__ Whf, const float* __restrict__ Whb,
    const float* __restrict__ xwf, const float* __restrict__ xwb,
    float* __restrict__ hf, float* __restrict__ hb,
    unsigned* __restrict__ progf, unsigned* __restrict__ progb)
{
  const int b    = blockIdx.x;
  const bool fwd = (b < KD3);
  const int bb   = fwd ? b : b - KD3;
  const int rb   = bb * RPB3;
  const float* __restrict__ Wh = fwd ? Whf : Whb;
  const float* __restrict__ xw = fwd ? xwf : xwb;
  float* __restrict__ hist     = fwd ? hf : hb;
  unsigned* __restrict__ prog  = fwd ? progf : progb;

  const int w     = threadIdx.x >> 6;   // wave 0..15
  const int lane  = threadIdx.x & 63;
  const int jbase = lane << 2;          // 0..252
  const int r0    = rb + 2 * w;         // this wave's two rows

  __shared__ __align__(16) float hs[H_N];   // 8 KB staged h_prev

  // One-time: weight slice into registers (64 VGPRs/lane), pinned so the
  // loads cannot be sunk into the loop.
  float4 wv[2][8];
#pragma unroll
  for (int q = 0; q < 2; ++q)
#pragma unroll
    for (int k = 0; k < 8; ++k)
      wv[q][k] = *(const float4*)(Wh + (size_t)(r0 + q) * H_N + k * 256 + jbase);
#pragma unroll
  for (int q = 0; q < 2; ++q)
#pragma unroll
    for (int k = 0; k < 8; ++k)
      asm volatile("" : "+v"(wv[q][k].x), "+v"(wv[q][k].y),
                        "+v"(wv[q][k].z), "+v"(wv[q][k].w));

  for (int s = 0; s < T_N; ++s) {
    const int t  = fwd ? s : (T_N - 1 - s);
    const int pt = fwd ? (t - 1) : (t + 1);

    // xw prefetch for our two rows (independent of h; overlaps the poll).
    float xwv0 = 0.f, xwv1 = 0.f;
    if (lane == 0) {
      xwv0 = xw[(size_t)t * H_N + r0 + 0];
      xwv1 = xw[(size_t)t * H_N + r0 + 1];
    }

    if (s > 0) {
      if (w == 0) {
        for (;;) {
          unsigned p = __hip_atomic_load(prog + lane, __ATOMIC_RELAXED,
                                         __HIP_MEMORY_SCOPE_AGENT);
          if (__all(p >= (unsigned)s)) break;
          __builtin_amdgcn_s_sleep(1);
        }
        asm volatile("" ::: "memory");   // compiler barrier only — no HW fence
      }
      __syncthreads();
      // Cooperative stage from LLC: 1024 threads x one 64-bit relaxed atomic.
      unsigned long long hv2 = __hip_atomic_load(
          (const unsigned long long*)(hist + (size_t)pt * H_N) + threadIdx.x,
          __ATOMIC_RELAXED, __HIP_MEMORY_SCOPE_AGENT);
      *((unsigned long long*)hs + threadIdx.x) = hv2;
      __syncthreads();
    } else {
      *((unsigned long long*)hs + threadIdx.x) = 0ull;
      __syncthreads();
    }

    // LDS fragments: conflict-free ds_read_b128 (lane-consecutive 16B).
    float acc0 = 0.f, acc1 = 0.f;
#pragma unroll
    for (int k = 0; k < 8; ++k) {
      float4 h4 = *(const float4*)(hs + k * 256 + jbase);
      acc0 = fmaf(wv[0][k].x, h4.x, acc0);
      acc0 = fmaf(wv[0][k].y, h4.y, acc0);
      acc0 = fmaf(wv[0][k].z, h4.z, acc0);
      acc0 = fmaf(wv[0][k].w, h4.w, acc0);
      acc1 = fmaf(wv[1][k].x, h4.x, acc1);
      acc1 = fmaf(wv[1][k].y, h4.y, acc1);
      acc1 = fmaf(wv[1][k].z, h4.z, acc1);
      acc1 = fmaf(wv[1][k].w, h4.w, acc1);
    }
#pragma unroll
    for (int off = 32; off > 0; off >>= 1) {
      acc0 += __shfl_xor(acc0, off, 64);
      acc1 += __shfl_xor(acc1, off, 64);
    }

    if (lane == 0) {
      union { float f; unsigned u; } h0, h1;
      h0.f = tanhf(acc0 + xwv0);
      h1.f = tanhf(acc1 + xwv1);
      unsigned* hu = (unsigned*)(hist + (size_t)t * H_N + r0);
      __hip_atomic_store(hu + 0, h0.u, __ATOMIC_RELAXED, __HIP_MEMORY_SCOPE_AGENT);
      __hip_atomic_store(hu + 1, h1.u, __ATOMIC_RELAXED, __HIP_MEMORY_SCOPE_AGENT);
    }

    // Compiler emits per-wave s_waitcnt vmcnt(0) before s_barrier: all 32
    // row-stores are ACKed at the LLC once the barrier releases.
    __syncthreads();
    if (threadIdx.x == 0)
      __hip_atomic_store(prog + bb, (unsigned)(s + 1), __ATOMIC_RELAXED,
                         __HIP_MEMORY_SCOPE_AGENT);
  }
}

extern "C" void kernel_launch(void* const* d_in, const int* in_sizes, int n_in,
                              void* d_out, int out_size, void* d_ws, size_t ws_size,
                              hipStream_t stream) {
  const float* x   = (const float*)d_in[0];
  const float* Wxf = (const float*)d_in[1];
  const float* Whf = (const float*)d_in[2];
  const float* bhf = (const float*)d_in[3];
  const float* Wxb = (const float*)d_in[4];
  const float* Whb = (const float*)d_in[5];
  const float* bhb = (const float*)d_in[6];
  const float* Wyf = (const float*)d_in[7];
  const float* Wyb = (const float*)d_in[8];
  const float* by  = (const float*)d_in[9];
  float* y = (float*)d_out;

  char* ws = (char*)d_ws;
  float* xwf      = (float*)(ws + XW_F_OFF);
  float* xwb      = (float*)(ws + XW_B_OFF);
  float* hf       = (float*)(ws + HF_OFF);
  float* hb       = (float*)(ws + HB_OFF);
  unsigned* progf = (unsigned*)(ws + PROG_OFF);
  unsigned* progb = progf + 64;   // +256 B, separate cache line

  hipLaunchKernelGGL(init_prog_kernel, dim3(1), dim3(128), 0, stream, progf);
  hipLaunchKernelGGL(gemm_xw_kernel, dim3(H_N / 64, T_N / 64, 2), dim3(256), 0, stream,
                     x, Wxf, bhf, Wxb, bhb, xwf, xwb);
  hipLaunchKernelGGL(recurrent_kernel, dim3(2 * KD3), dim3(RTH3), 0, stream,
                     Whf, Whb, xwf, xwb, hf, hb, progf, progb);
  hipLaunchKernelGGL(gemm_out_kernel, dim3(OUT_N / 64, T_N / 64), dim3(256), 0, stream,
                     hf, hb, Wyf, Wyb, by, y);
}